// Round 15
// baseline (66.604 us; speedup 1.0000x reference)
//
#include <hip/hip_runtime.h>

#define NUM_CLASSES 80
#define N13 507
#define N26 2028
#define N52 8112
#define NANCH (N13 + N26 + N52)   // 10647
#define BATCH 64
#define MAXB 100
#define NB 3720                    // float-bit buckets: (bits>>14) - 0xFC00, scores in (0.5, 79)
#define BOFF 0xFC00u
#define KPT 11                     // ceil(NANCH/1024)
#define TOPK 1024                  // region target size
#define LCAP 4096                  // LDS ring capacity (power of 2)
#define LMASK (LCAP-1)

typedef unsigned long long u64;

// EXACT division-free IoU>0.5 test (validated on-data R13/R14): for un>0,
// RN(inter/un) > 0.5f  <=>  (double)inter > (0.5 + 2^-25)*(double)un  (product exact in f64).
__device__ __forceinline__ bool sup_cmp(float inter, float un) {
    return (un > 0.f) && ((double)inter > 0x1.000001p-1 * (double)un);
}

__device__ __forceinline__ u64 readlane64(u64 v, int l) {
    unsigned int lo = (unsigned int)__builtin_amdgcn_readlane((int)(v & 0xFFFFFFFFull), l);
    unsigned int hi = (unsigned int)__builtin_amdgcn_readlane((int)(v >> 32), l);
    return ((u64)hi << 32) | (u64)lo;
}

__device__ __forceinline__ void bases_of(int b, int a, const float*& cb, const float*& pb,
    const float* c13, const float* p13, const float* c26, const float* p26,
    const float* c52, const float* p52)
{
    if (a < N13)          { cb = c13 + ((size_t)b*N13 + a)*NUM_CLASSES;           pb = p13 + (size_t)b*N13 + a; }
    else if (a < N13+N26) { cb = c26 + ((size_t)b*N26 + (a-N13))*NUM_CLASSES;     pb = p26 + (size_t)b*N26 + (a-N13); }
    else                  { cb = c52 + ((size_t)b*N52 + (a-N13-N26))*NUM_CLASSES; pb = p52 + (size_t)b*N52 + (a-N13-N26); }
}

// ---------- Phase 1: score = p * (float)argmax(classes); 4 lanes/anchor, 2 anchors/cluster ----
// All 10 float4 loads issued before any compute: 2x memory-level parallelism per wave.
__global__ __launch_bounds__(256) void score_kernel(
    const float* __restrict__ c13, const float* __restrict__ p13,
    const float* __restrict__ c26, const float* __restrict__ p26,
    const float* __restrict__ c52, const float* __restrict__ p52,
    float* __restrict__ scores)
{
    const int cl  = threadIdx.x >> 2;            // 64 clusters / block
    const int sub = threadIdx.x & 3;
    const int b   = blockIdx.y;
    const int a0  = blockIdx.x * 128 + cl * 2;
    const int a1  = a0 + 1;
    const bool h0 = a0 < NANCH, h1 = a1 < NANCH;

    const float *cb0 = nullptr, *pb0 = nullptr, *cb1 = nullptr, *pb1 = nullptr;
    if (h0) bases_of(b, a0, cb0, pb0, c13, p13, c26, p26, c52, p52);
    if (h1) bases_of(b, a1, cb1, pb1, c13, p13, c26, p26, c52, p52);

    float4 va[5], vb[5];
    #pragma unroll
    for (int q = 0; q < 5; ++q) va[q] = h0 ? *(const float4*)(cb0 + q*16 + sub*4) : make_float4(-2.f,-2.f,-2.f,-2.f);
    #pragma unroll
    for (int q = 0; q < 5; ++q) vb[q] = h1 ? *(const float4*)(cb1 + q*16 + sub*4) : make_float4(-2.f,-2.f,-2.f,-2.f);

    // anchor 0
    {
        float mx = -1.0f; int mi = 0;
        #pragma unroll
        for (int q = 0; q < 5; ++q) {
            int cb = q*16 + sub*4;               // classes ascend within each lane
            if (va[q].x > mx) { mx = va[q].x; mi = cb+0; }   // strict > keeps FIRST max
            if (va[q].y > mx) { mx = va[q].y; mi = cb+1; }
            if (va[q].z > mx) { mx = va[q].z; mi = cb+2; }
            if (va[q].w > mx) { mx = va[q].w; mi = cb+3; }
        }
        #pragma unroll
        for (int off = 1; off < 4; off <<= 1) {  // tie -> lower class index (jnp.argmax)
            float ov = __shfl_xor(mx, off);
            int   oi = __shfl_xor(mi, off);
            if (ov > mx || (ov == mx && oi < mi)) { mx = ov; mi = oi; }
        }
        if (sub == 0 && h0) scores[(size_t)b*NANCH + a0] = pb0[0] * (float)mi;
    }
    // anchor 1
    {
        float mx = -1.0f; int mi = 0;
        #pragma unroll
        for (int q = 0; q < 5; ++q) {
            int cb = q*16 + sub*4;
            if (vb[q].x > mx) { mx = vb[q].x; mi = cb+0; }
            if (vb[q].y > mx) { mx = vb[q].y; mi = cb+1; }
            if (vb[q].z > mx) { mx = vb[q].z; mi = cb+2; }
            if (vb[q].w > mx) { mx = vb[q].w; mi = cb+3; }
        }
        #pragma unroll
        for (int off = 1; off < 4; off <<= 1) {
            float ov = __shfl_xor(mx, off);
            int   oi = __shfl_xor(mi, off);
            if (ov > mx || (ov == mx && oi < mi)) { mx = ov; mi = oi; }
        }
        if (sub == 0 && h1) scores[(size_t)b*NANCH + a1] = pb1[0] * (float)mi;
    }
}

__device__ __forceinline__ float4 load_box(const float* __restrict__ b13,
                                           const float* __restrict__ b26,
                                           const float* __restrict__ b52,
                                           int b, int n)
{
    if (n < N13)          return *(const float4*)(b13 + ((size_t)b*N13 + n)*4);
    else if (n < N13+N26) return *(const float4*)(b26 + ((size_t)b*N26 + (n-N13))*4);
    else                  return *(const float4*)(b52 + ((size_t)b*N52 + (n-N13-N26))*4);
}

// ---------------- Phase 2: top-K counting-sort + wave-parallel scan NMS ----------------
// greedy argmax-NMS == scan in (score desc, idx asc) order, accept iff IoU<=0.5 vs all accepted.
// Scan: 1 barrier/chunk; kill-rows built distributed via shfl; ALL waves redundantly resolve
// (deterministic identical trajectory) so no second barrier; parity-buffered kmat/sup_lds.
__global__ __launch_bounds__(1024) void nms_sort_scan(
    const float* __restrict__ scores,
    const float* __restrict__ b13, const float* __restrict__ b26, const float* __restrict__ b52,
    float* __restrict__ out)
{
    const int b    = blockIdx.x;
    const int tid  = threadIdx.x;
    const int lane = tid & 63;
    const int wid  = tid >> 6;

    __shared__ u64 lst[LCAP];                   // 32 KB ring of sorted candidates
    __shared__ unsigned int cnt[NB];            // 14.9 KB
    __shared__ unsigned int wtot[16];
    __shared__ float4 acc4[MAXB];               // accepted canonical boxes (y1,x1,y2,x2)
    __shared__ u64 kmat[2][64];                 // parity-buffered kill rows
    __shared__ u64 sup_lds[2][16];              // parity-buffered supp ballots
    __shared__ float outrec[MAXB][6];
    __shared__ int T_s, L_s;

    const float* sc = scores + (size_t)b * NANCH;

    float sreg[KPT];
    #pragma unroll
    for (int k = 0; k < KPT; ++k) {
        int n = tid + (k << 10);
        sreg[k] = (n < NANCH) ? sc[n] : 0.f;
    }

    for (int i = tid; i < NB; i += 1024) cnt[i] = 0u;
    __syncthreads();

    #pragma unroll
    for (int k = 0; k < KPT; ++k) {
        float s = sreg[k];
        if (s > 0.5f) {
            unsigned int bk = (__float_as_uint(s) >> 14) - BOFF;
            if (bk >= NB) bk = NB - 1;
            atomicAdd(&cnt[bk], 1u);
        }
    }
    __syncthreads();

    unsigned int loc[4]; unsigned int s4 = 0u;
    #pragma unroll
    for (int q = 0; q < 4; ++q) {
        int r = tid*4 + q;
        unsigned int v = (r < NB) ? cnt[NB-1-r] : 0u;
        loc[q] = v; s4 += v;
    }
    unsigned int incl = s4;
    #pragma unroll
    for (int off = 1; off < 64; off <<= 1) {
        unsigned int v = __shfl_up(incl, off);
        if (lane >= off) incl += v;
    }
    if (lane == 63) wtot[wid] = incl;
    __syncthreads();
    unsigned int wexcl = 0u, total = 0u;
    #pragma unroll
    for (int w = 0; w < 16; ++w) { unsigned int t = wtot[w]; if (w < wid) wexcl += t; total += t; }
    unsigned int run = wexcl + (incl - s4);
    if (tid == 0) { T_s = 0; L_s = (int)total; }
    __syncthreads();
    #pragma unroll
    for (int q = 0; q < 4; ++q) {
        int r = tid*4 + q;
        if (r < NB) {
            int bk = NB-1-r;
            unsigned int c = loc[q];
            if (run < TOPK && run + c >= TOPK) { T_s = bk; L_s = (int)(run + c); }
            cnt[bk] = run;
            run += c;
        }
    }
    __syncthreads();
    const int total_i = (int)total;
    int Treg = T_s;
    int regionEnd = L_s;

    #pragma unroll
    for (int k = 0; k < KPT; ++k) {
        float s = sreg[k];
        if (s > 0.5f) {
            unsigned int bits = __float_as_uint(s);
            unsigned int bk = (bits >> 14) - BOFF;
            if (bk >= NB) bk = NB - 1;
            if ((int)bk >= Treg) {
                unsigned int pos = atomicAdd(&cnt[bk], 1u);
                lst[pos & LMASK] = ((u64)bits << 32) | (u64)(0xFFFFFFFFu - (unsigned int)(tid + (k<<10)));
            }
        }
    }
    __syncthreads();

    {
        u64 kk[4]; int tt[4];
        #pragma unroll
        for (int i = 0; i < 4; ++i) {
            int p = tid + (i << 10);
            tt[i] = -1; kk[i] = 0ull;
            if (p < regionEnd) {
                u64 key = lst[p & LMASK];
                unsigned int bk = (unsigned int)(key >> 46) - BOFF;
                if (bk >= NB) bk = NB - 1;
                unsigned int st = (bk+1 < NB) ? cnt[bk+1] : 0u;
                unsigned int e  = cnt[bk];
                unsigned int rank = 0u;
                for (unsigned int q = st; q < e; ++q) rank += (lst[q & LMASK] > key) ? 1u : 0u;
                kk[i] = key; tt[i] = (int)(st + rank);
            }
        }
        __syncthreads();
        #pragma unroll
        for (int i = 0; i < 4; ++i) if (tt[i] >= 0) lst[tt[i] & LMASK] = kk[i];
        __syncthreads();
    }

    // ---- wave-parallel chunked scan: ONE barrier/chunk ----
    int accN = 0;
    u64 key = 0ull; float4 bb = make_float4(0.f,0.f,0.f,0.f); float s = 0.f;
    if (lane < regionEnd) {
        key = lst[lane];
        unsigned int n = 0xFFFFFFFFu - (unsigned int)(key & 0xFFFFFFFFull);
        s = __uint_as_float((unsigned int)(key >> 32));
        bb = load_box(b13, b26, b52, b, (int)n);
    }

    int c = 0;
    while (c < total_i && accN < MAXB) {
        // ---- region extension (fallback; never taken for bench data) ----
        while (c + 64 > regionEnd && regionEnd < total_i) {
            int K2 = regionEnd + TOPK;
            if (tid == 0) { T_s = 0; L_s = total_i; }
            __syncthreads();
            for (int bk = tid; bk < Treg; bk += 1024) {
                unsigned int stv = cnt[bk];
                unsigned int ev  = (bk == 0) ? (unsigned int)total_i : cnt[bk-1];
                if (stv < (unsigned int)K2 && ev >= (unsigned int)K2) { T_s = bk; L_s = (int)ev; }
            }
            __syncthreads();
            int T2 = T_s, L2 = L_s;
            #pragma unroll
            for (int k = 0; k < KPT; ++k) {
                float sv = sreg[k];
                if (sv > 0.5f) {
                    unsigned int bits = __float_as_uint(sv);
                    int bk = (int)((bits >> 14) - BOFF);
                    if (bk >= NB) bk = NB - 1;
                    if (bk >= T2 && bk < Treg) {
                        unsigned int pos = atomicAdd(&cnt[bk], 1u);
                        lst[pos & LMASK] = ((u64)bits << 32) | (u64)(0xFFFFFFFFu - (unsigned int)(tid + (k<<10)));
                    }
                }
            }
            __syncthreads();
            {
                u64 kk[4]; int tt[4];
                #pragma unroll
                for (int i = 0; i < 4; ++i) {
                    int p = regionEnd + tid + (i << 10);
                    tt[i] = -1; kk[i] = 0ull;
                    if (p < L2) {
                        u64 k2 = lst[p & LMASK];
                        unsigned int bk = (unsigned int)(k2 >> 46) - BOFF;
                        if (bk >= NB) bk = NB - 1;
                        unsigned int st = (bk+1 < NB) ? cnt[bk+1] : 0u;
                        unsigned int e  = cnt[bk];
                        unsigned int rank = 0u;
                        for (unsigned int q = st; q < e; ++q) rank += (lst[q & LMASK] > k2) ? 1u : 0u;
                        kk[i] = k2; tt[i] = (int)(st + rank);
                    }
                }
                __syncthreads();
                #pragma unroll
                for (int i = 0; i < 4; ++i) if (tt[i] >= 0) lst[tt[i] & LMASK] = kk[i];
                __syncthreads();
            }
            Treg = T2; regionEnd = L2;
            key = 0ull; bb = make_float4(0.f,0.f,0.f,0.f); s = 0.f;
            if (c + lane < regionEnd) {
                key = lst[(c + lane) & LMASK];
                unsigned int n = 0xFFFFFFFFu - (unsigned int)(key & 0xFFFFFFFFull);
                s = __uint_as_float((unsigned int)(key >> 32));
                bb = load_box(b13, b26, b52, b, (int)n);
            }
        }

        int m = regionEnd - c; if (m > 64) m = 64;
        const int par = (c >> 6) & 1;
        float oy1 = bb.x, ox1 = bb.y, oy2 = bb.z, ox2 = bb.w, cs = s;
        float y1 = fminf(oy1, oy2), y2 = fmaxf(oy1, oy2);
        float x1 = fminf(ox1, ox2), x2 = fmaxf(ox1, ox2);
        float ar = (y2-y1)*(x2-x1);

        // prefetch next chunk
        int nc = c + 64;
        if (nc + lane < regionEnd) {
            key = lst[(nc + lane) & LMASK];
            unsigned int n = 0xFFFFFFFFu - (unsigned int)(key & 0xFFFFFFFFull);
            s = __uint_as_float((unsigned int)(key >> 32));
            bb = load_box(b13, b26, b52, b, (int)n);
        } else { s = 0.f; bb = make_float4(0.f,0.f,0.f,0.f); }

        // --- acc-check: wave w tests accepted slice {w, w+16, ...}; pipelined LDS reads ---
        bool supp = (lane >= m);
        #pragma unroll 2
        for (int j = wid; j < accN; j += 16) {
            float4 aj = acc4[j];                 // broadcast read, conflict-free
            float jar = (aj.z - aj.x) * (aj.w - aj.y);   // bit-identical to ref's area
            float iy1=fmaxf(y1,aj.x), iy2=fminf(y2,aj.z);
            float ix1=fmaxf(x1,aj.y), ix2=fminf(x2,aj.w);
            float inter=fmaxf(iy2-iy1,0.f)*fmaxf(ix2-ix1,0.f);
            float un=(ar+jar)-inter;
            supp |= sup_cmp(inter, un);
        }
        u64 bal = __ballot(supp);
        if (lane == 0) sup_lds[par][wid] = bal;

        // --- distributed kill-row build: wave w builds rows {w, w+16, w+32, w+48} via shfl ---
        #pragma unroll
        for (int q = 0; q < 4; ++q) {
            int rr = wid + (q << 4);
            float ry1=__shfl(y1,rr), rx1=__shfl(x1,rr), ry2=__shfl(y2,rr), rx2=__shfl(x2,rr);
            float rar=__shfl(ar,rr);
            float iy1=fmaxf(y1,ry1), iy2=fminf(y2,ry2);
            float ix1=fmaxf(x1,rx1), ix2=fminf(x2,rx2);
            float inter=fmaxf(iy2-iy1,0.f)*fmaxf(ix2-ix1,0.f);
            float un=(ar+rar)-inter;
            u64 kb = __ballot(sup_cmp(inter, un));
            if (lane == 0) kmat[par][rr] = kb;
        }
        __syncthreads();                         // the ONLY barrier per chunk

        // --- ALL waves: redundant deterministic resolve (identical trajectory) ---
        {
            u64 myrow = kmat[par][lane];
            u64 B = 0ull;
            #pragma unroll
            for (int w = 0; w < 16; ++w) B |= sup_lds[par][w];
            u64 valid_m = (m >= 64) ? ~0ull : ((1ull << m) - 1ull);
            u64 rem = (~B) & valid_m;
            u64 accmask = 0ull;
            const int start = accN;
            while (rem && accN < MAXB) {
                int j = __builtin_ctzll(rem);
                u64 rowj = readlane64(myrow, j);
                accmask |= (1ull << j);
                rem &= ~rowj;
                rem &= ~(1ull << j);
                accN++;
            }
            // every wave's accepted lanes write identical records (benign duplicates)
            if (accmask & (1ull << lane)) {
                int pos = start + (int)__popcll(accmask & ((1ull << lane) - 1ull));
                acc4[pos] = make_float4(y1, x1, y2, x2);
                outrec[pos][0]=fminf(fmaxf(oy1,0.f),1.f);
                outrec[pos][1]=fminf(fmaxf(ox1,0.f),1.f);
                outrec[pos][2]=fminf(fmaxf(oy2,0.f),1.f);
                outrec[pos][3]=fminf(fmaxf(ox2,0.f),1.f);
                outrec[pos][4]=cs;
                outrec[pos][5]=0.f;
            }
        }
        c += 64;                                 // no second barrier
    }

    // ---- block-wide output write (accN is block-uniform) ----
    __syncthreads();
    float* outp = out + (size_t)b * (MAXB*6);
    for (int i = tid; i < MAXB*6; i += 1024) {
        int t = i / 6;
        outp[i] = (t < accN) ? outrec[t][i % 6] : 0.f;
    }
    if (tid == 0) out[(size_t)BATCH*(MAXB*6) + b] = (float)accN;
}

extern "C" void kernel_launch(void* const* d_in, const int* in_sizes, int n_in,
                              void* d_out, int out_size, void* d_ws, size_t ws_size,
                              hipStream_t stream)
{
    const float* bbox13 = (const float*)d_in[0];
    const float* p13    = (const float*)d_in[1];
    const float* c13    = (const float*)d_in[2];
    const float* bbox26 = (const float*)d_in[3];
    const float* p26    = (const float*)d_in[4];
    const float* c26    = (const float*)d_in[5];
    const float* bbox52 = (const float*)d_in[6];
    const float* p52    = (const float*)d_in[7];
    const float* c52    = (const float*)d_in[8];
    float* out    = (float*)d_out;
    float* scores = (float*)d_ws;   // 64*10647*4 = 2.7 MB

    dim3 g1((NANCH + 127)/128, BATCH);
    score_kernel<<<g1, 256, 0, stream>>>(c13, p13, c26, p26, c52, p52, scores);
    nms_sort_scan<<<BATCH, 1024, 0, stream>>>(scores, bbox13, bbox26, bbox52, out);
}

// Round 16
// 58.714 us; speedup vs baseline: 1.1344x; 1.1344x over previous
//
#include <hip/hip_runtime.h>

#define NUM_CLASSES 80
#define N13 507
#define N26 2028
#define N52 8112
#define NANCH (N13 + N26 + N52)   // 10647
#define BATCH 64
#define MAXB 100
#define NB 3720                    // float-bit buckets: (bits>>14) - 0xFC00, scores in (0.5, 79)
#define BOFF 0xFC00u
#define KPT 11                     // ceil(NANCH/1024)
#define TOPK 1024                  // region target size
#define LCAP 4096                  // LDS ring capacity (power of 2)
#define LMASK (LCAP-1)
#define APB 64                     // anchors per 256-thread block (4 lanes/anchor)

typedef unsigned long long u64;

// EXACT division-free IoU>0.5 test (validated on-data R13/R14): for un>0,
// RN(inter/un) > 0.5f  <=>  (double)inter > (0.5 + 2^-25)*(double)un  (product exact in f64).
__device__ __forceinline__ bool sup_cmp(float inter, float un) {
    return (un > 0.f) && ((double)inter > 0x1.000001p-1 * (double)un);
}

__device__ __forceinline__ u64 readlane64(u64 v, int l) {
    unsigned int lo = (unsigned int)__builtin_amdgcn_readlane((int)(v & 0xFFFFFFFFull), l);
    unsigned int hi = (unsigned int)__builtin_amdgcn_readlane((int)(v >> 32), l);
    return ((u64)hi << 32) | (u64)lo;
}

// ---------------- Phase 1: score = p * (float)argmax(classes), 4 lanes per anchor -------------
// (R14 version: 1 anchor/cluster, measured VGPR=32 -> full occupancy, ~7.3 TB/s L3 streaming)
__global__ __launch_bounds__(256) void score_kernel(
    const float* __restrict__ c13, const float* __restrict__ p13,
    const float* __restrict__ c26, const float* __restrict__ p26,
    const float* __restrict__ c52, const float* __restrict__ p52,
    float* __restrict__ scores)
{
    int a   = blockIdx.x * APB + (threadIdx.x >> 2);
    int sub = threadIdx.x & 3;
    int b   = blockIdx.y;
    if (a >= NANCH) return;
    const float* cbase; const float* pbase;
    if (a < N13)            { cbase = c13 + ((size_t)b*N13 + a) * NUM_CLASSES;           pbase = p13 + (size_t)b*N13 + a; }
    else if (a < N13+N26)   { cbase = c26 + ((size_t)b*N26 + (a-N13)) * NUM_CLASSES;     pbase = p26 + (size_t)b*N26 + (a-N13); }
    else                    { cbase = c52 + ((size_t)b*N52 + (a-N13-N26)) * NUM_CLASSES; pbase = p52 + (size_t)b*N52 + (a-N13-N26); }
    float mx = -1.0f; int mi = 0;
    #pragma unroll
    for (int q = 0; q < 5; ++q) {
        float4 v = *(const float4*)(cbase + q*16 + sub*4);
        int cb = q*16 + sub*4;                   // classes ascend within each lane
        if (v.x > mx) { mx = v.x; mi = cb+0; }   // strict > keeps FIRST max
        if (v.y > mx) { mx = v.y; mi = cb+1; }
        if (v.z > mx) { mx = v.z; mi = cb+2; }
        if (v.w > mx) { mx = v.w; mi = cb+3; }
    }
    // merge across the 4-lane group: larger value wins; tie -> lower class index (jnp.argmax)
    #pragma unroll
    for (int off = 1; off < 4; off <<= 1) {
        float ov = __shfl_xor(mx, off);
        int   oi = __shfl_xor(mi, off);
        if (ov > mx || (ov == mx && oi < mi)) { mx = ov; mi = oi; }
    }
    if (sub == 0) scores[(size_t)b*NANCH + a] = pbase[0] * (float)mi;
}

__device__ __forceinline__ float4 load_box(const float* __restrict__ b13,
                                           const float* __restrict__ b26,
                                           const float* __restrict__ b52,
                                           int b, int n)
{
    if (n < N13)          return *(const float4*)(b13 + ((size_t)b*N13 + n)*4);
    else if (n < N13+N26) return *(const float4*)(b26 + ((size_t)b*N26 + (n-N13))*4);
    else                  return *(const float4*)(b52 + ((size_t)b*N52 + (n-N13-N26))*4);
}

// ---------------- Phase 2: top-K counting-sort + wave-parallel scan NMS (R14 structure) -------
// greedy argmax-NMS == scan in (score desc, idx asc) order, accept iff IoU<=0.5 vs all accepted.
__global__ __launch_bounds__(1024) void nms_sort_scan(
    const float* __restrict__ scores,
    const float* __restrict__ b13, const float* __restrict__ b26, const float* __restrict__ b52,
    float* __restrict__ out)
{
    const int b    = blockIdx.x;
    const int tid  = threadIdx.x;
    const int lane = tid & 63;
    const int wid  = tid >> 6;

    __shared__ u64 lst[LCAP];                   // 32 KB ring of sorted candidates
    __shared__ unsigned int cnt[NB];            // 14.9 KB
    __shared__ unsigned int wtot[16];
    __shared__ float4 acc4[MAXB];               // accepted canonical boxes (y1,x1,y2,x2)
    __shared__ u64 kmat[64];                    // per-chunk kill rows (row r = victims of r)
    __shared__ u64 sup_lds[16];
    __shared__ float outrec[MAXB][6];
    __shared__ int accN_s, T_s, L_s;

    const float* sc = scores + (size_t)b * NANCH;

    float sreg[KPT];
    #pragma unroll
    for (int k = 0; k < KPT; ++k) {
        int n = tid + (k << 10);
        sreg[k] = (n < NANCH) ? sc[n] : 0.f;
    }

    for (int i = tid; i < NB; i += 1024) cnt[i] = 0u;
    if (tid == 0) accN_s = 0;
    __syncthreads();

    #pragma unroll
    for (int k = 0; k < KPT; ++k) {
        float s = sreg[k];
        if (s > 0.5f) {
            unsigned int bk = (__float_as_uint(s) >> 14) - BOFF;
            if (bk >= NB) bk = NB - 1;
            atomicAdd(&cnt[bk], 1u);
        }
    }
    __syncthreads();

    unsigned int loc[4]; unsigned int s4 = 0u;
    #pragma unroll
    for (int q = 0; q < 4; ++q) {
        int r = tid*4 + q;
        unsigned int v = (r < NB) ? cnt[NB-1-r] : 0u;
        loc[q] = v; s4 += v;
    }
    unsigned int incl = s4;
    #pragma unroll
    for (int off = 1; off < 64; off <<= 1) {
        unsigned int v = __shfl_up(incl, off);
        if (lane >= off) incl += v;
    }
    if (lane == 63) wtot[wid] = incl;
    __syncthreads();
    unsigned int wexcl = 0u, total = 0u;
    #pragma unroll
    for (int w = 0; w < 16; ++w) { unsigned int t = wtot[w]; if (w < wid) wexcl += t; total += t; }
    unsigned int run = wexcl + (incl - s4);
    if (tid == 0) { T_s = 0; L_s = (int)total; }
    __syncthreads();
    #pragma unroll
    for (int q = 0; q < 4; ++q) {
        int r = tid*4 + q;
        if (r < NB) {
            int bk = NB-1-r;
            unsigned int c = loc[q];
            if (run < TOPK && run + c >= TOPK) { T_s = bk; L_s = (int)(run + c); }
            cnt[bk] = run;
            run += c;
        }
    }
    __syncthreads();
    const int total_i = (int)total;
    int Treg = T_s;
    int regionEnd = L_s;

    #pragma unroll
    for (int k = 0; k < KPT; ++k) {
        float s = sreg[k];
        if (s > 0.5f) {
            unsigned int bits = __float_as_uint(s);
            unsigned int bk = (bits >> 14) - BOFF;
            if (bk >= NB) bk = NB - 1;
            if ((int)bk >= Treg) {
                unsigned int pos = atomicAdd(&cnt[bk], 1u);
                lst[pos & LMASK] = ((u64)bits << 32) | (u64)(0xFFFFFFFFu - (unsigned int)(tid + (k<<10)));
            }
        }
    }
    __syncthreads();

    {
        u64 kk[4]; int tt[4];
        #pragma unroll
        for (int i = 0; i < 4; ++i) {
            int p = tid + (i << 10);
            tt[i] = -1; kk[i] = 0ull;
            if (p < regionEnd) {
                u64 key = lst[p & LMASK];
                unsigned int bk = (unsigned int)(key >> 46) - BOFF;
                if (bk >= NB) bk = NB - 1;
                unsigned int st = (bk+1 < NB) ? cnt[bk+1] : 0u;
                unsigned int e  = cnt[bk];
                unsigned int rank = 0u;
                for (unsigned int q = st; q < e; ++q) rank += (lst[q & LMASK] > key) ? 1u : 0u;
                kk[i] = key; tt[i] = (int)(st + rank);
            }
        }
        __syncthreads();
        #pragma unroll
        for (int i = 0; i < 4; ++i) if (tt[i] >= 0) lst[tt[i] & LMASK] = kk[i];
        __syncthreads();
    }

    // ---- wave-parallel chunked scan (R14: 2 barriers/chunk, wave0 scalar resolve) ----
    int accN = 0;
    u64 key = 0ull; float4 bb = make_float4(0.f,0.f,0.f,0.f); float s = 0.f;
    if (lane < regionEnd) {
        key = lst[lane];
        unsigned int n = 0xFFFFFFFFu - (unsigned int)(key & 0xFFFFFFFFull);
        s = __uint_as_float((unsigned int)(key >> 32));
        bb = load_box(b13, b26, b52, b, (int)n);
    }

    int c = 0;
    while (c < total_i && accN < MAXB) {
        // ---- region extension (fallback; never taken for bench data) ----
        while (c + 64 > regionEnd && regionEnd < total_i) {
            int K2 = regionEnd + TOPK;
            if (tid == 0) { T_s = 0; L_s = total_i; }
            __syncthreads();
            for (int bk = tid; bk < Treg; bk += 1024) {
                unsigned int stv = cnt[bk];
                unsigned int ev  = (bk == 0) ? (unsigned int)total_i : cnt[bk-1];
                if (stv < (unsigned int)K2 && ev >= (unsigned int)K2) { T_s = bk; L_s = (int)ev; }
            }
            __syncthreads();
            int T2 = T_s, L2 = L_s;
            #pragma unroll
            for (int k = 0; k < KPT; ++k) {
                float sv = sreg[k];
                if (sv > 0.5f) {
                    unsigned int bits = __float_as_uint(sv);
                    int bk = (int)((bits >> 14) - BOFF);
                    if (bk >= NB) bk = NB - 1;
                    if (bk >= T2 && bk < Treg) {
                        unsigned int pos = atomicAdd(&cnt[bk], 1u);
                        lst[pos & LMASK] = ((u64)bits << 32) | (u64)(0xFFFFFFFFu - (unsigned int)(tid + (k<<10)));
                    }
                }
            }
            __syncthreads();
            {
                u64 kk[4]; int tt[4];
                #pragma unroll
                for (int i = 0; i < 4; ++i) {
                    int p = regionEnd + tid + (i << 10);
                    tt[i] = -1; kk[i] = 0ull;
                    if (p < L2) {
                        u64 k2 = lst[p & LMASK];
                        unsigned int bk = (unsigned int)(k2 >> 46) - BOFF;
                        if (bk >= NB) bk = NB - 1;
                        unsigned int st = (bk+1 < NB) ? cnt[bk+1] : 0u;
                        unsigned int e  = cnt[bk];
                        unsigned int rank = 0u;
                        for (unsigned int q = st; q < e; ++q) rank += (lst[q & LMASK] > k2) ? 1u : 0u;
                        kk[i] = k2; tt[i] = (int)(st + rank);
                    }
                }
                __syncthreads();
                #pragma unroll
                for (int i = 0; i < 4; ++i) if (tt[i] >= 0) lst[tt[i] & LMASK] = kk[i];
                __syncthreads();
            }
            Treg = T2; regionEnd = L2;
            key = 0ull; bb = make_float4(0.f,0.f,0.f,0.f); s = 0.f;
            if (c + lane < regionEnd) {
                key = lst[(c + lane) & LMASK];
                unsigned int n = 0xFFFFFFFFu - (unsigned int)(key & 0xFFFFFFFFull);
                s = __uint_as_float((unsigned int)(key >> 32));
                bb = load_box(b13, b26, b52, b, (int)n);
            }
        }

        int m = regionEnd - c; if (m > 64) m = 64;
        float oy1 = bb.x, ox1 = bb.y, oy2 = bb.z, ox2 = bb.w, cs = s;
        float y1 = fminf(oy1, oy2), y2 = fmaxf(oy1, oy2);
        float x1 = fminf(ox1, ox2), x2 = fmaxf(ox1, ox2);
        float ar = (y2-y1)*(x2-x1);

        // prefetch next chunk
        int nc = c + 64;
        if (nc + lane < regionEnd) {
            key = lst[(nc + lane) & LMASK];
            unsigned int n = 0xFFFFFFFFu - (unsigned int)(key & 0xFFFFFFFFull);
            s = __uint_as_float((unsigned int)(key >> 32));
            bb = load_box(b13, b26, b52, b, (int)n);
        } else { s = 0.f; bb = make_float4(0.f,0.f,0.f,0.f); }

        // --- distributed kill-row build FIRST (shfl/VALU-only; overlaps later LDS reads) ---
        // IoU symmetric + bitwise-commutative ops => row(r) == column(r); R12/R13 validated.
        #pragma unroll
        for (int q = 0; q < 4; ++q) {
            int rr = wid + (q << 4);
            float ry1=__shfl(y1,rr), rx1=__shfl(x1,rr), ry2=__shfl(y2,rr), rx2=__shfl(x2,rr);
            float rar=__shfl(ar,rr);
            float iy1=fmaxf(y1,ry1), iy2=fminf(y2,ry2);
            float ix1=fmaxf(x1,rx1), ix2=fminf(x2,rx2);
            float inter=fmaxf(iy2-iy1,0.f)*fmaxf(ix2-ix1,0.f);
            float un=(ar+rar)-inter;
            u64 kb = __ballot(sup_cmp(inter, un));
            if (lane == 0) kmat[rr] = kb;
        }

        // --- acc-check: wave w tests accepted slice {w, w+16, ...}; pipelined LDS reads ---
        bool supp = (lane >= m);
        #pragma unroll 2
        for (int j = wid; j < accN; j += 16) {
            float4 aj = acc4[j];                 // broadcast read, conflict-free
            float jar = (aj.z - aj.x) * (aj.w - aj.y);   // bit-identical to ref's area
            float iy1=fmaxf(y1,aj.x), iy2=fminf(y2,aj.z);
            float ix1=fmaxf(x1,aj.y), ix2=fminf(x2,aj.w);
            float inter=fmaxf(iy2-iy1,0.f)*fmaxf(ix2-ix1,0.f);
            float un=(ar+jar)-inter;
            supp |= sup_cmp(inter, un);
        }
        u64 bal = __ballot(supp);
        if (lane == 0) sup_lds[wid] = bal;
        __syncthreads();                         // sup_lds + kmat visible

        // --- wave0: one-shot row fetch + pure readlane resolve ---
        if (wid == 0) {
            u64 myrow = kmat[lane];              // single ds_read_b64
            u64 B = 0ull;
            #pragma unroll
            for (int w = 0; w < 16; ++w) B |= sup_lds[w];
            u64 valid_m = (m >= 64) ? ~0ull : ((1ull << m) - 1ull);
            u64 rem = (~B) & valid_m;
            u64 accmask = 0ull;
            const int start = accN;
            while (rem && accN < MAXB) {
                int j = __builtin_ctzll(rem);
                u64 rowj = readlane64(myrow, j); // victims of j (== killers of j by symmetry)
                accmask |= (1ull << j);
                rem &= ~rowj;
                rem &= ~(1ull << j);
                accN++;
            }
            if (accmask & (1ull << lane)) {
                int pos = start + (int)__popcll(accmask & ((1ull << lane) - 1ull));
                acc4[pos] = make_float4(y1, x1, y2, x2);
                outrec[pos][0]=fminf(fmaxf(oy1,0.f),1.f);
                outrec[pos][1]=fminf(fmaxf(ox1,0.f),1.f);
                outrec[pos][2]=fminf(fmaxf(oy2,0.f),1.f);
                outrec[pos][3]=fminf(fmaxf(ox2,0.f),1.f);
                outrec[pos][4]=cs;
                outrec[pos][5]=0.f;
            }
            if (lane == 0) accN_s = accN;
        }
        __syncthreads();
        accN = accN_s;
        c += 64;
    }

    // ---- block-wide output write ----
    const int accNf = accN_s;
    float* outp = out + (size_t)b * (MAXB*6);
    for (int i = tid; i < MAXB*6; i += 1024) {
        int t = i / 6;
        outp[i] = (t < accNf) ? outrec[t][i % 6] : 0.f;
    }
    if (tid == 0) out[(size_t)BATCH*(MAXB*6) + b] = (float)accNf;
}

extern "C" void kernel_launch(void* const* d_in, const int* in_sizes, int n_in,
                              void* d_out, int out_size, void* d_ws, size_t ws_size,
                              hipStream_t stream)
{
    const float* bbox13 = (const float*)d_in[0];
    const float* p13    = (const float*)d_in[1];
    const float* c13    = (const float*)d_in[2];
    const float* bbox26 = (const float*)d_in[3];
    const float* p26    = (const float*)d_in[4];
    const float* c26    = (const float*)d_in[5];
    const float* bbox52 = (const float*)d_in[6];
    const float* p52    = (const float*)d_in[7];
    const float* c52    = (const float*)d_in[8];
    float* out    = (float*)d_out;
    float* scores = (float*)d_ws;   // 64*10647*4 = 2.7 MB

    dim3 g1((NANCH + APB - 1)/APB, BATCH);
    score_kernel<<<g1, 256, 0, stream>>>(c13, p13, c26, p26, c52, p52, scores);
    nms_sort_scan<<<BATCH, 1024, 0, stream>>>(scores, bbox13, bbox26, bbox52, out);
}

// Round 17
// 57.581 us; speedup vs baseline: 1.1567x; 1.0197x over previous
//
#include <hip/hip_runtime.h>

#define NUM_CLASSES 80
#define N13 507
#define N26 2028
#define N52 8112
#define NANCH (N13 + N26 + N52)   // 10647
#define BATCH 64
#define MAXB 100
#define NB 3720                    // float-bit buckets: (bits>>14) - 0xFC00, scores in (0.5, 79)
#define BOFF 0xFC00u
#define KPT 11                     // ceil(NANCH/1024)
#define TOPK 1024                  // region target size
#define LCAP 4096                  // LDS ring capacity (power of 2)
#define LMASK (LCAP-1)
#define APB 64                     // anchors per 256-thread block (4 lanes/anchor)

typedef unsigned long long u64;

// EXACT division-free IoU>0.5 test (validated on-data R13/R14): for un>0,
// RN(inter/un) > 0.5f  <=>  (double)inter > (0.5 + 2^-25)*(double)un  (product exact in f64).
__device__ __forceinline__ bool sup_cmp(float inter, float un) {
    return (un > 0.f) && ((double)inter > 0x1.000001p-1 * (double)un);
}

__device__ __forceinline__ u64 readlane64(u64 v, int l) {
    unsigned int lo = (unsigned int)__builtin_amdgcn_readlane((int)(v & 0xFFFFFFFFull), l);
    unsigned int hi = (unsigned int)__builtin_amdgcn_readlane((int)(v >> 32), l);
    return ((u64)hi << 32) | (u64)lo;
}

// ---------------- Phase 1: score = p * (float)argmax(classes), 4 lanes per anchor -------------
// (R14 version: VGPR=32 -> full occupancy; ~7.3 TB/s L3 streaming = measured machine ceiling)
__global__ __launch_bounds__(256) void score_kernel(
    const float* __restrict__ c13, const float* __restrict__ p13,
    const float* __restrict__ c26, const float* __restrict__ p26,
    const float* __restrict__ c52, const float* __restrict__ p52,
    float* __restrict__ scores)
{
    int a   = blockIdx.x * APB + (threadIdx.x >> 2);
    int sub = threadIdx.x & 3;
    int b   = blockIdx.y;
    if (a >= NANCH) return;
    const float* cbase; const float* pbase;
    if (a < N13)            { cbase = c13 + ((size_t)b*N13 + a) * NUM_CLASSES;           pbase = p13 + (size_t)b*N13 + a; }
    else if (a < N13+N26)   { cbase = c26 + ((size_t)b*N26 + (a-N13)) * NUM_CLASSES;     pbase = p26 + (size_t)b*N26 + (a-N13); }
    else                    { cbase = c52 + ((size_t)b*N52 + (a-N13-N26)) * NUM_CLASSES; pbase = p52 + (size_t)b*N52 + (a-N13-N26); }
    float mx = -1.0f; int mi = 0;
    #pragma unroll
    for (int q = 0; q < 5; ++q) {
        float4 v = *(const float4*)(cbase + q*16 + sub*4);
        int cb = q*16 + sub*4;                   // classes ascend within each lane
        if (v.x > mx) { mx = v.x; mi = cb+0; }   // strict > keeps FIRST max
        if (v.y > mx) { mx = v.y; mi = cb+1; }
        if (v.z > mx) { mx = v.z; mi = cb+2; }
        if (v.w > mx) { mx = v.w; mi = cb+3; }
    }
    // merge across the 4-lane group: larger value wins; tie -> lower class index (jnp.argmax)
    #pragma unroll
    for (int off = 1; off < 4; off <<= 1) {
        float ov = __shfl_xor(mx, off);
        int   oi = __shfl_xor(mi, off);
        if (ov > mx || (ov == mx && oi < mi)) { mx = ov; mi = oi; }
    }
    if (sub == 0) scores[(size_t)b*NANCH + a] = pbase[0] * (float)mi;
}

__device__ __forceinline__ float4 load_box(const float* __restrict__ b13,
                                           const float* __restrict__ b26,
                                           const float* __restrict__ b52,
                                           int b, int n)
{
    if (n < N13)          return *(const float4*)(b13 + ((size_t)b*N13 + n)*4);
    else if (n < N13+N26) return *(const float4*)(b26 + ((size_t)b*N26 + (n-N13))*4);
    else                  return *(const float4*)(b52 + ((size_t)b*N52 + (n-N13-N26))*4);
}

// ---------------- Phase 2: top-K counting-sort + wave-parallel scan NMS (R14 verbatim) --------
// greedy argmax-NMS == scan in (score desc, idx asc) order, accept iff IoU<=0.5 vs all accepted.
__global__ __launch_bounds__(1024) void nms_sort_scan(
    const float* __restrict__ scores,
    const float* __restrict__ b13, const float* __restrict__ b26, const float* __restrict__ b52,
    float* __restrict__ out)
{
    const int b    = blockIdx.x;
    const int tid  = threadIdx.x;
    const int lane = tid & 63;
    const int wid  = tid >> 6;

    __shared__ u64 lst[LCAP];                   // 32 KB ring of sorted candidates
    __shared__ unsigned int cnt[NB];            // 14.9 KB
    __shared__ unsigned int wtot[16];
    __shared__ float4 acc4[MAXB];               // accepted canonical boxes (y1,x1,y2,x2)
    __shared__ u64 kmat[64];                    // per-chunk kill rows (row r = victims of r)
    __shared__ u64 sup_lds[16];
    __shared__ float outrec[MAXB][6];
    __shared__ int accN_s, T_s, L_s;

    const float* sc = scores + (size_t)b * NANCH;

    float sreg[KPT];
    #pragma unroll
    for (int k = 0; k < KPT; ++k) {
        int n = tid + (k << 10);
        sreg[k] = (n < NANCH) ? sc[n] : 0.f;
    }

    for (int i = tid; i < NB; i += 1024) cnt[i] = 0u;
    if (tid == 0) accN_s = 0;
    __syncthreads();

    #pragma unroll
    for (int k = 0; k < KPT; ++k) {
        float s = sreg[k];
        if (s > 0.5f) {
            unsigned int bk = (__float_as_uint(s) >> 14) - BOFF;
            if (bk >= NB) bk = NB - 1;
            atomicAdd(&cnt[bk], 1u);
        }
    }
    __syncthreads();

    unsigned int loc[4]; unsigned int s4 = 0u;
    #pragma unroll
    for (int q = 0; q < 4; ++q) {
        int r = tid*4 + q;
        unsigned int v = (r < NB) ? cnt[NB-1-r] : 0u;
        loc[q] = v; s4 += v;
    }
    unsigned int incl = s4;
    #pragma unroll
    for (int off = 1; off < 64; off <<= 1) {
        unsigned int v = __shfl_up(incl, off);
        if (lane >= off) incl += v;
    }
    if (lane == 63) wtot[wid] = incl;
    __syncthreads();
    unsigned int wexcl = 0u, total = 0u;
    #pragma unroll
    for (int w = 0; w < 16; ++w) { unsigned int t = wtot[w]; if (w < wid) wexcl += t; total += t; }
    unsigned int run = wexcl + (incl - s4);
    if (tid == 0) { T_s = 0; L_s = (int)total; }
    __syncthreads();
    #pragma unroll
    for (int q = 0; q < 4; ++q) {
        int r = tid*4 + q;
        if (r < NB) {
            int bk = NB-1-r;
            unsigned int c = loc[q];
            if (run < TOPK && run + c >= TOPK) { T_s = bk; L_s = (int)(run + c); }
            cnt[bk] = run;
            run += c;
        }
    }
    __syncthreads();
    const int total_i = (int)total;
    int Treg = T_s;
    int regionEnd = L_s;

    #pragma unroll
    for (int k = 0; k < KPT; ++k) {
        float s = sreg[k];
        if (s > 0.5f) {
            unsigned int bits = __float_as_uint(s);
            unsigned int bk = (bits >> 14) - BOFF;
            if (bk >= NB) bk = NB - 1;
            if ((int)bk >= Treg) {
                unsigned int pos = atomicAdd(&cnt[bk], 1u);
                lst[pos & LMASK] = ((u64)bits << 32) | (u64)(0xFFFFFFFFu - (unsigned int)(tid + (k<<10)));
            }
        }
    }
    __syncthreads();

    {
        u64 kk[4]; int tt[4];
        #pragma unroll
        for (int i = 0; i < 4; ++i) {
            int p = tid + (i << 10);
            tt[i] = -1; kk[i] = 0ull;
            if (p < regionEnd) {
                u64 key = lst[p & LMASK];
                unsigned int bk = (unsigned int)(key >> 46) - BOFF;
                if (bk >= NB) bk = NB - 1;
                unsigned int st = (bk+1 < NB) ? cnt[bk+1] : 0u;
                unsigned int e  = cnt[bk];
                unsigned int rank = 0u;
                for (unsigned int q = st; q < e; ++q) rank += (lst[q & LMASK] > key) ? 1u : 0u;
                kk[i] = key; tt[i] = (int)(st + rank);
            }
        }
        __syncthreads();
        #pragma unroll
        for (int i = 0; i < 4; ++i) if (tt[i] >= 0) lst[tt[i] & LMASK] = kk[i];
        __syncthreads();
    }

    // ---- wave-parallel chunked scan (2 barriers/chunk, wave0 scalar resolve) ----
    int accN = 0;
    u64 key = 0ull; float4 bb = make_float4(0.f,0.f,0.f,0.f); float s = 0.f;
    if (lane < regionEnd) {
        key = lst[lane];
        unsigned int n = 0xFFFFFFFFu - (unsigned int)(key & 0xFFFFFFFFull);
        s = __uint_as_float((unsigned int)(key >> 32));
        bb = load_box(b13, b26, b52, b, (int)n);
    }

    int c = 0;
    while (c < total_i && accN < MAXB) {
        // ---- region extension (fallback; never taken for bench data) ----
        while (c + 64 > regionEnd && regionEnd < total_i) {
            int K2 = regionEnd + TOPK;
            if (tid == 0) { T_s = 0; L_s = total_i; }
            __syncthreads();
            for (int bk = tid; bk < Treg; bk += 1024) {
                unsigned int stv = cnt[bk];
                unsigned int ev  = (bk == 0) ? (unsigned int)total_i : cnt[bk-1];
                if (stv < (unsigned int)K2 && ev >= (unsigned int)K2) { T_s = bk; L_s = (int)ev; }
            }
            __syncthreads();
            int T2 = T_s, L2 = L_s;
            #pragma unroll
            for (int k = 0; k < KPT; ++k) {
                float sv = sreg[k];
                if (sv > 0.5f) {
                    unsigned int bits = __float_as_uint(sv);
                    int bk = (int)((bits >> 14) - BOFF);
                    if (bk >= NB) bk = NB - 1;
                    if (bk >= T2 && bk < Treg) {
                        unsigned int pos = atomicAdd(&cnt[bk], 1u);
                        lst[pos & LMASK] = ((u64)bits << 32) | (u64)(0xFFFFFFFFu - (unsigned int)(tid + (k<<10)));
                    }
                }
            }
            __syncthreads();
            {
                u64 kk[4]; int tt[4];
                #pragma unroll
                for (int i = 0; i < 4; ++i) {
                    int p = regionEnd + tid + (i << 10);
                    tt[i] = -1; kk[i] = 0ull;
                    if (p < L2) {
                        u64 k2 = lst[p & LMASK];
                        unsigned int bk = (unsigned int)(k2 >> 46) - BOFF;
                        if (bk >= NB) bk = NB - 1;
                        unsigned int st = (bk+1 < NB) ? cnt[bk+1] : 0u;
                        unsigned int e  = cnt[bk];
                        unsigned int rank = 0u;
                        for (unsigned int q = st; q < e; ++q) rank += (lst[q & LMASK] > k2) ? 1u : 0u;
                        kk[i] = k2; tt[i] = (int)(st + rank);
                    }
                }
                __syncthreads();
                #pragma unroll
                for (int i = 0; i < 4; ++i) if (tt[i] >= 0) lst[tt[i] & LMASK] = kk[i];
                __syncthreads();
            }
            Treg = T2; regionEnd = L2;
            key = 0ull; bb = make_float4(0.f,0.f,0.f,0.f); s = 0.f;
            if (c + lane < regionEnd) {
                key = lst[(c + lane) & LMASK];
                unsigned int n = 0xFFFFFFFFu - (unsigned int)(key & 0xFFFFFFFFull);
                s = __uint_as_float((unsigned int)(key >> 32));
                bb = load_box(b13, b26, b52, b, (int)n);
            }
        }

        int m = regionEnd - c; if (m > 64) m = 64;
        float oy1 = bb.x, ox1 = bb.y, oy2 = bb.z, ox2 = bb.w, cs = s;
        float y1 = fminf(oy1, oy2), y2 = fmaxf(oy1, oy2);
        float x1 = fminf(ox1, ox2), x2 = fmaxf(ox1, ox2);
        float ar = (y2-y1)*(x2-x1);

        // prefetch next chunk
        int nc = c + 64;
        if (nc + lane < regionEnd) {
            key = lst[(nc + lane) & LMASK];
            unsigned int n = 0xFFFFFFFFu - (unsigned int)(key & 0xFFFFFFFFull);
            s = __uint_as_float((unsigned int)(key >> 32));
            bb = load_box(b13, b26, b52, b, (int)n);
        } else { s = 0.f; bb = make_float4(0.f,0.f,0.f,0.f); }

        // --- acc-check: wave w tests accepted slice {w, w+16, ...}; pipelined LDS reads ---
        bool supp = (lane >= m);
        #pragma unroll 2
        for (int j = wid; j < accN; j += 16) {
            float4 aj = acc4[j];                 // broadcast read, conflict-free
            float jar = (aj.z - aj.x) * (aj.w - aj.y);   // bit-identical to ref's area
            float iy1=fmaxf(y1,aj.x), iy2=fminf(y2,aj.z);
            float ix1=fmaxf(x1,aj.y), ix2=fminf(x2,aj.w);
            float inter=fmaxf(iy2-iy1,0.f)*fmaxf(ix2-ix1,0.f);
            float un=(ar+jar)-inter;
            supp |= sup_cmp(inter, un);
        }
        u64 bal = __ballot(supp);
        if (lane == 0) sup_lds[wid] = bal;

        // --- distributed kill-row build: wave w builds rows {w, w+16, w+32, w+48} via shfl ---
        // IoU symmetric + bitwise-commutative ops => row(r) == column(r); R12/R13 validated.
        #pragma unroll
        for (int q = 0; q < 4; ++q) {
            int rr = wid + (q << 4);
            float ry1=__shfl(y1,rr), rx1=__shfl(x1,rr), ry2=__shfl(y2,rr), rx2=__shfl(x2,rr);
            float rar=__shfl(ar,rr);
            float iy1=fmaxf(y1,ry1), iy2=fminf(y2,ry2);
            float ix1=fmaxf(x1,rx1), ix2=fminf(x2,rx2);
            float inter=fmaxf(iy2-iy1,0.f)*fmaxf(ix2-ix1,0.f);
            float un=(ar+rar)-inter;
            u64 kb = __ballot(sup_cmp(inter, un));
            if (lane == 0) kmat[rr] = kb;
        }
        __syncthreads();                         // sup_lds + kmat visible

        // --- wave0: one-shot row fetch + pure readlane resolve ---
        if (wid == 0) {
            u64 myrow = kmat[lane];              // single ds_read_b64
            u64 B = 0ull;
            #pragma unroll
            for (int w = 0; w < 16; ++w) B |= sup_lds[w];
            u64 valid_m = (m >= 64) ? ~0ull : ((1ull << m) - 1ull);
            u64 rem = (~B) & valid_m;
            u64 accmask = 0ull;
            const int start = accN;
            while (rem && accN < MAXB) {
                int j = __builtin_ctzll(rem);
                u64 rowj = readlane64(myrow, j); // victims of j (== killers of j by symmetry)
                accmask |= (1ull << j);
                rem &= ~rowj;
                rem &= ~(1ull << j);
                accN++;
            }
            if (accmask & (1ull << lane)) {
                int pos = start + (int)__popcll(accmask & ((1ull << lane) - 1ull));
                acc4[pos] = make_float4(y1, x1, y2, x2);
                outrec[pos][0]=fminf(fmaxf(oy1,0.f),1.f);
                outrec[pos][1]=fminf(fmaxf(ox1,0.f),1.f);
                outrec[pos][2]=fminf(fmaxf(oy2,0.f),1.f);
                outrec[pos][3]=fminf(fmaxf(ox2,0.f),1.f);
                outrec[pos][4]=cs;
                outrec[pos][5]=0.f;
            }
            if (lane == 0) accN_s = accN;
        }
        __syncthreads();
        accN = accN_s;
        c += 64;
    }

    // ---- block-wide output write ----
    const int accNf = accN_s;
    float* outp = out + (size_t)b * (MAXB*6);
    for (int i = tid; i < MAXB*6; i += 1024) {
        int t = i / 6;
        outp[i] = (t < accNf) ? outrec[t][i % 6] : 0.f;
    }
    if (tid == 0) out[(size_t)BATCH*(MAXB*6) + b] = (float)accNf;
}

extern "C" void kernel_launch(void* const* d_in, const int* in_sizes, int n_in,
                              void* d_out, int out_size, void* d_ws, size_t ws_size,
                              hipStream_t stream)
{
    const float* bbox13 = (const float*)d_in[0];
    const float* p13    = (const float*)d_in[1];
    const float* c13    = (const float*)d_in[2];
    const float* bbox26 = (const float*)d_in[3];
    const float* p26    = (const float*)d_in[4];
    const float* c26    = (const float*)d_in[5];
    const float* bbox52 = (const float*)d_in[6];
    const float* p52    = (const float*)d_in[7];
    const float* c52    = (const float*)d_in[8];
    float* out    = (float*)d_out;
    float* scores = (float*)d_ws;   // 64*10647*4 = 2.7 MB

    dim3 g1((NANCH + APB - 1)/APB, BATCH);
    score_kernel<<<g1, 256, 0, stream>>>(c13, p13, c26, p26, c52, p52, scores);
    nms_sort_scan<<<BATCH, 1024, 0, stream>>>(scores, bbox13, bbox26, bbox52, out);
}